// Round 2
// baseline (868.489 us; speedup 1.0000x reference)
//
#include <hip/hip_runtime.h>
#include <math.h>

#define D 256
#define TOPK 1024
#define EPS 1e-8f

typedef __attribute__((ext_vector_type(8))) short short8;
typedef __attribute__((ext_vector_type(4))) float f32x4;

__device__ __forceinline__ unsigned encf(float f){
  unsigned b = __float_as_uint(f);
  return b ^ ((unsigned)((int)b >> 31) | 0x80000000u);
}
__device__ __forceinline__ float decf(unsigned u){
  unsigned b = (u & 0x80000000u) ? (u ^ 0x80000000u) : ~u;
  return __uint_as_float(b);
}

// ---------------------------------------------------------------------------
// K1: convert W_e (256x256 block of W) into 3 bf16 split matrices laid out in
// MFMA b-frag order, compute wd[3][256] (distance-column contribution),
// |q|, zero histograms + scalars.
// Frag order per col c: elem idx = c*256 + chunk*32 + g*8 + h*4 + e
//   where k = 32*chunk + 16*h + 4*g + e   (A/B operand: k = 4*(lane>>4)+e+16h)
// ---------------------------------------------------------------------------
__global__ __launch_bounds__(256) void k1_setup(
    const float* __restrict__ emb, const float* __restrict__ dtab,
    const float* __restrict__ W, const int* __restrict__ srcp,
    short* __restrict__ Wbh, short* __restrict__ Wbm, short* __restrict__ Wbl,
    float* __restrict__ WD, float* __restrict__ QN,
    unsigned* __restrict__ SC, unsigned* __restrict__ H0)
{
  int tid = threadIdx.x;
  int gid = blockIdx.x*256 + tid;
  if (gid < 6144) H0[gid] = 0u;          // H0,H1,H2 contiguous (2048 each)
  if (gid == 0){
    SC[0]=0u;                 // MAXE (encoded max logit)
    ((float*)SC)[1]=0.0f;     // SUME
    SC[2]=0u;                 // EQC
    SC[3]=0u;                 // PFX
    SC[4]=(unsigned)TOPK;     // KP (remaining quota)
  }
  if (blockIdx.x < 256){
    int c = blockIdx.x;       // output col (= W row j)
    int k = tid;              // k index
    float f = W[(size_t)c*258 + k];
    unsigned u  = __float_as_uint(f);
    unsigned hb = u & 0xffff0000u;
    float r = f - __uint_as_float(hb);
    unsigned mb = __float_as_uint(r) & 0xffff0000u;
    float r2 = r - __uint_as_float(mb);
    unsigned lb = __float_as_uint(r2) & 0xffff0000u;
    int idx = c*256 + (k>>5)*32 + ((k>>2)&3)*8 + ((k>>4)&1)*4 + (k&3);
    Wbh[idx] = (short)(hb>>16);
    Wbm[idx] = (short)(mb>>16);
    Wbl[idx] = (short)(lb>>16);
  } else {
    int k = tid;
    float w6 = W[(size_t)k*258 + 256], w7 = W[(size_t)k*258 + 257];
    WD[k]     = w6*dtab[0] + w7*dtab[1];
    WD[256+k] = w6*dtab[2] + w7*dtab[3];
    WD[512+k] = w6*dtab[4] + w7*dtab[5];
    int src = srcp[0];
    float qk = emb[(size_t)src*D + k];
    __shared__ float red[256];
    red[tid]=qk*qk; __syncthreads();
    for (int s2=128;s2>0;s2>>=1){ if (tid<s2) red[tid]+=red[tid+s2]; __syncthreads(); }
    if (tid==0) QN[0] = sqrtf(red[0]);
  }
}

// ---------------------------------------------------------------------------
// K2: MFMA bf16x3 GEMM t = x * W_e^T fused with cosine/logit epilogue.
// Block = 4 waves, 64 rows. Wave w owns rows base..base+15 x all 256 cols:
// acc = 16 col-frags (f32x4). K=256 in 8 chunks of 32. Per chunk:
//   a-frags from 2 float4 global loads, split in-register to 3x bf16x8
//   b-frags: 16B short8 loads from pre-swizzled Wb{h,m,l} (L2-resident)
//   6 split pairs: (h,h)(m,h)(l,h)(h,m)(m,m)(h,l) -> ~2^-24 rel error
// No LDS operands, no barriers in main loop. Epilogue: per lane 4 rows x 16
// cols partials of Q=||t+wd||^2 and s=(t+wd).q, shfl_xor reduce over the
// 16-lane group, per-row encode + fused pass-0 histogram.
// ---------------------------------------------------------------------------
__global__ __launch_bounds__(256) void k2_main(
    const float* __restrict__ emb, const int* __restrict__ dist,
    const int* __restrict__ srcp,
    const short* __restrict__ Wbh, const short* __restrict__ Wbm,
    const short* __restrict__ Wbl,
    const float* __restrict__ WD, const float* __restrict__ QN,
    float* __restrict__ Sv, unsigned* __restrict__ UK,
    unsigned* __restrict__ SC, unsigned* __restrict__ H0, int N)
{
  int tid = threadIdx.x;
  int wave = tid >> 6;
  int lane = tid & 63;
  int g = lane >> 4;         // 16-lane group (k-block / C row-group)
  int c0 = lane & 15;        // A row within strip / B,C col within frag
  int base = blockIdx.x*64 + wave*16;

  __shared__ float wdL[3][256];
  __shared__ float qL[256];
  __shared__ unsigned h[2048];
  for (int i=tid;i<768;i+=256) ((float*)wdL)[i] = WD[i];
  {
    int src = srcp[0];
    qL[tid] = emb[(size_t)src*D + tid];
  }
  for (int i=tid;i<2048;i+=256) h[i]=0u;
  __syncthreads();

  int rowA = base + c0;
  const float* xp = emb + (size_t)((rowA < N) ? rowA : 0)*D + 4*g;

  f32x4 acc[16];
  #pragma unroll
  for (int f=0;f<16;++f) acc[f] = (f32x4){0.f,0.f,0.f,0.f};

  size_t bco = (size_t)c0*256 + (size_t)g*8;
  const short* Bh = Wbh + bco;
  const short* Bm_ = Wbm + bco;
  const short* Bl_ = Wbl + bco;

  float4 x0 = *(const float4*)(xp);
  float4 x1 = *(const float4*)(xp + 4);

  for (int ch=0; ch<8; ++ch){
    // prefetch next chunk's X (wraps harmlessly on last iter)
    int chn = (ch+1)&7;
    float4 nx0 = *(const float4*)(xp + 8*chn);
    float4 nx1 = *(const float4*)(xp + 8*chn + 4);

    float xs[8] = {x0.x,x0.y,x0.z,x0.w, x1.x,x1.y,x1.z,x1.w};
    short8 ah, am, al;
    #pragma unroll
    for (int e=0;e<8;++e){
      float f = xs[e];
      unsigned u  = __float_as_uint(f);
      unsigned hb = u & 0xffff0000u;
      float r = f - __uint_as_float(hb);
      unsigned mb = __float_as_uint(r) & 0xffff0000u;
      float r2 = r - __uint_as_float(mb);
      unsigned lb = __float_as_uint(r2) & 0xffff0000u;
      ah[e] = (short)(hb>>16);
      am[e] = (short)(mb>>16);
      al[e] = (short)(lb>>16);
    }

    const short* bh = Bh + ch*32;
    const short* bm = Bm_ + ch*32;
    const short* bl = Bl_ + ch*32;
    short8 b[16];
    // ---- sw = hi: pairs (h,h),(m,h),(l,h)
    #pragma unroll
    for (int f=0;f<16;++f) b[f] = *(const short8*)(bh + (size_t)f*4096);
    #pragma unroll
    for (int f=0;f<16;++f) acc[f] = __builtin_amdgcn_mfma_f32_16x16x32_bf16(ah, b[f], acc[f], 0,0,0);
    #pragma unroll
    for (int f=0;f<16;++f) acc[f] = __builtin_amdgcn_mfma_f32_16x16x32_bf16(am, b[f], acc[f], 0,0,0);
    #pragma unroll
    for (int f=0;f<16;++f) acc[f] = __builtin_amdgcn_mfma_f32_16x16x32_bf16(al, b[f], acc[f], 0,0,0);
    // ---- sw = mid: pairs (h,m),(m,m)
    #pragma unroll
    for (int f=0;f<16;++f) b[f] = *(const short8*)(bm + (size_t)f*4096);
    #pragma unroll
    for (int f=0;f<16;++f) acc[f] = __builtin_amdgcn_mfma_f32_16x16x32_bf16(ah, b[f], acc[f], 0,0,0);
    #pragma unroll
    for (int f=0;f<16;++f) acc[f] = __builtin_amdgcn_mfma_f32_16x16x32_bf16(am, b[f], acc[f], 0,0,0);
    // ---- sw = lo: pair (h,l)
    #pragma unroll
    for (int f=0;f<16;++f) b[f] = *(const short8*)(bl + (size_t)f*4096);
    #pragma unroll
    for (int f=0;f<16;++f) acc[f] = __builtin_amdgcn_mfma_f32_16x16x32_bf16(ah, b[f], acc[f], 0,0,0);

    x0 = nx0; x1 = nx1;
  }

  // ------------------ epilogue ------------------
  int dvr[4], di[4];
  #pragma unroll
  for (int r=0;r<4;++r){
    int rr = base + 4*g + r;
    dvr[r] = (rr < N) ? dist[rr] : 3;
    int d = dvr[r]-1; di[r] = d<0?0:(d>2?2:d);
  }
  float Qp[4] = {0.f,0.f,0.f,0.f};
  float Sp[4] = {0.f,0.f,0.f,0.f};
  #pragma unroll
  for (int f=0;f<16;++f){
    int c = 16*f + c0;
    float qc = qL[c];
    #pragma unroll
    for (int r=0;r<4;++r){
      float v = acc[f][r] + wdL[di[r]][c];
      Qp[r] = fmaf(v, v, Qp[r]);
      Sp[r] = fmaf(v, qc, Sp[r]);
    }
  }
  #pragma unroll
  for (int off=1; off<16; off<<=1){
    #pragma unroll
    for (int r=0;r<4;++r){
      Qp[r] += __shfl_xor(Qp[r], off);
      Sp[r] += __shfl_xor(Sp[r], off);
    }
  }

  float qn = QN[0];
  float s_for_max = -INFINITY;
  if (c0 < 4){
    int row = base + 4*g + c0;
    if (row < N){
      float Q = (c0==0)?Qp[0]:(c0==1)?Qp[1]:(c0==2)?Qp[2]:Qp[3];
      float s = (c0==0)?Sp[0]:(c0==1)?Sp[1]:(c0==2)?Sp[2]:Sp[3];
      int dv  = (c0==0)?dvr[0]:(c0==1)?dvr[1]:(c0==2)?dvr[2]:dvr[3];
      float den = fmaxf(sqrtf(Q), EPS) * fmaxf(qn, EPS);
      float cosv = s/den;
      float wgt = (dv==1)?1.5f:((dv==2)?2.0f:1.0f);
      float wv = (dv<=2)? cosv*wgt : -INFINITY;
      unsigned u = encf(wv);
      Sv[row] = s; UK[row] = u;
      if (u > 0x007FFFFFu) atomicAdd(&h[u>>21],1u);
      s_for_max = s;
    }
  }
  float m = s_for_max;
  #pragma unroll
  for (int off=32;off>0;off>>=1) m = fmaxf(m, __shfl_down(m, off));
  if (lane==0) atomicMax(&SC[0], encf(m));
  __syncthreads();
  for (int i=tid;i<2048;i+=256){ unsigned v=h[i]; if (v) atomicAdd(&H0[i], v); }
}

// ---------------------------------------------------------------------------
// Radix-select histogram passes 1,2 (LDS-privatized).  (unchanged)
// ---------------------------------------------------------------------------
__global__ __launch_bounds__(256) void kh_hist(
    const unsigned* __restrict__ UK, const unsigned* __restrict__ SC,
    unsigned* __restrict__ Hp, int pass, int N)
{
  __shared__ unsigned h[2048];
  int bins = (pass==2)?1024:2048;
  int tid = threadIdx.x;
  for (int i=tid;i<bins;i+=256) h[i]=0u;
  __syncthreads();
  unsigned pfx = SC[3];
  int n = blockIdx.x*256 + tid;
  if (n < N){
    unsigned u = UK[n];
    bool incl; unsigned bin;
    if (pass==1){ incl = ((u>>21)==pfx); bin = (u>>10)&2047u; }
    else { incl = ((u>>10)==pfx); bin = u & 1023u; }
    if (incl) atomicAdd(&h[bin], 1u);
  }
  __syncthreads();
  for (int i=tid;i<bins;i+=256){ unsigned v=h[i]; if (v) atomicAdd(&Hp[i], v); }
}

__global__ __launch_bounds__(256) void ks_scan(
    const unsigned* __restrict__ Hp, unsigned* __restrict__ SC, int pass)
{
  __shared__ unsigned h[2048];
  __shared__ unsigned part[256];
  int bins=(pass==2)?1024:2048;
  int per = bins/256;
  int tid=threadIdx.x;
  unsigned ps=0;
  for (int i=0;i<per;++i){ unsigned v=Hp[tid*per+i]; h[tid*per+i]=v; ps+=v; }
  part[tid]=ps;
  __syncthreads();
  if (tid==0){
    unsigned Kp = SC[4];
    unsigned cum=0;
    int sc2=0;
    for (int t=255;t>=0;--t){
      if (cum + part[t] >= Kp){ sc2=t; break; }
      cum += part[t];
    }
    int sel = sc2*per;
    for (int b2=sc2*per+per-1; b2>=sc2*per; --b2){
      if (cum + h[b2] >= Kp){ sel=b2; break; }
      cum += h[b2];
    }
    SC[4] = Kp - cum;                         // remaining quota among == bin
    int bitsp = (pass==2)?10:11;
    SC[3] = (SC[3] << bitsp) | (unsigned)sel; // extend prefix
  }
}

// ---------------------------------------------------------------------------
// K6: write mask (topk-strict | dist==1 | src), collect ==T list, sum-exp.
// (unchanged)
// ---------------------------------------------------------------------------
__global__ __launch_bounds__(256) void k6_final(
    const int* __restrict__ dist, const int* __restrict__ srcp,
    const float* __restrict__ Sv, const unsigned* __restrict__ UK,
    unsigned* __restrict__ SC, unsigned* __restrict__ EQL,
    float* __restrict__ out, int N)
{
  int tid=threadIdx.x;
  int n=blockIdx.x*256+tid;
  unsigned T = SC[3];
  float M = decf(SC[0]);
  int src = srcp[0];
  float e=0.f;
  if (n<N){
    unsigned u = UK[n];
    int dv = dist[n];
    bool base = (u>T) || (dv==1) || (n==src);
    out[1+n] = base ? 1.0f : 0.0f;
    if (u==T){
      unsigned i = atomicAdd(&SC[2], 1u);
      if (i < 4096u) EQL[i] = (unsigned)n;
    }
    e = expf(Sv[n]-M);
  }
  __shared__ float red[256];
  red[tid]=e; __syncthreads();
  for (int st=128;st>0;st>>=1){ if (tid<st) red[tid]+=red[tid+st]; __syncthreads(); }
  if (tid==0) atomicAdd((float*)&SC[1], red[0]);
}

// ---------------------------------------------------------------------------
// K7: loss = L*lse - sum(logits[labels]); resolve ==T ties lowest-index-first.
// (unchanged)
// ---------------------------------------------------------------------------
__global__ __launch_bounds__(256) void k7_loss(
    const int* __restrict__ labels, const float* __restrict__ Sv,
    unsigned* __restrict__ SC, const unsigned* __restrict__ EQL,
    float* __restrict__ out, int L)
{
  __shared__ float red[256];
  __shared__ unsigned lst[4096];
  int tid=threadIdx.x;
  float v=0.f;
  if (tid<L) v = Sv[labels[tid]];
  red[tid]=v; __syncthreads();
  for (int st=128;st>0;st>>=1){ if (tid<st) red[tid]+=red[tid+st]; __syncthreads(); }
  if (tid==0){
    float M = decf(SC[0]);
    float se = ((const float*)SC)[1];
    out[0] = (float)L*(M + logf(se)) - red[0];
  }
  unsigned cnt = SC[2]; if (cnt>4096u) cnt=4096u;
  unsigned quota = SC[4];
  for (unsigned i=tid;i<cnt;i+=256u) lst[i]=EQL[i];
  __syncthreads();
  if (cnt <= quota){
    for (unsigned i=tid;i<cnt;i+=256u) out[1+lst[i]] = 1.0f;
  } else {
    for (unsigned i=tid;i<cnt;i+=256u){
      unsigned me=lst[i]; unsigned rank=0;
      for (unsigned j=0;j<cnt;++j) rank += (lst[j]<me)?1u:0u;
      if (rank<quota) out[1+me]=1.0f;   // stable tie-break: lowest index wins
    }
  }
}

extern "C" void kernel_launch(void* const* d_in, const int* in_sizes, int n_in,
                              void* d_out, int out_size, void* d_ws, size_t ws_size,
                              hipStream_t stream)
{
  const float* emb  = (const float*)d_in[0];
  const float* dtab = (const float*)d_in[1];
  const float* W    = (const float*)d_in[2];
  const int* dist   = (const int*)d_in[3];
  const int* labels = (const int*)d_in[4];
  const int* srcp   = (const int*)d_in[5];
  float* out = (float*)d_out;
  int N = in_sizes[3];
  int L = in_sizes[4];

  float* ws = (float*)d_ws;
  short* Wbh = (short*)ws;              // 65536 bf16 (as shorts)
  short* Wbm = Wbh + 65536;             // 65536
  short* Wbl = Wbm + 65536;             // 65536
  float* WD  = (float*)(Wbl + 65536);   // 768
  float* QN  = WD + 768;                // 1
  unsigned* SC = (unsigned*)(QN + 1);   // 8 scalars
  unsigned* H0 = SC + 8;                // 2048
  unsigned* H1 = H0 + 2048;             // 2048
  unsigned* H2 = H1 + 2048;             // 2048 (1024 used)
  float* Sv = (float*)(H2 + 2048);      // N
  unsigned* UK = (unsigned*)(Sv + N);   // N
  unsigned* EQL = UK + N;               // 4096

  int grid  = (N + 255)/256;
  int gridm = (N + 63)/64;
  k1_setup<<<257,256,0,stream>>>(emb, dtab, W, srcp, Wbh, Wbm, Wbl, WD, QN, SC, H0);
  k2_main<<<gridm,256,0,stream>>>(emb, dist, srcp, Wbh, Wbm, Wbl, WD, QN, Sv, UK, SC, H0, N);
  ks_scan<<<1,256,0,stream>>>(H0, SC, 0);
  kh_hist<<<grid,256,0,stream>>>(UK, SC, H1, 1, N);
  ks_scan<<<1,256,0,stream>>>(H1, SC, 1);
  kh_hist<<<grid,256,0,stream>>>(UK, SC, H2, 2, N);
  ks_scan<<<1,256,0,stream>>>(H2, SC, 2);
  k6_final<<<grid,256,0,stream>>>(dist, srcp, Sv, UK, SC, EQL, out, N);
  k7_loss<<<1,256,0,stream>>>(labels, Sv, SC, EQL, out, L);
}

// Round 3
// 502.455 us; speedup vs baseline: 1.7285x; 1.7285x over previous
//
#include <hip/hip_runtime.h>
#include <math.h>

#define D 256
#define TOPK 1024
#define EPS 1e-8f

typedef __attribute__((ext_vector_type(8))) short short8;
typedef __attribute__((ext_vector_type(4))) float f32x4;

__device__ __forceinline__ unsigned encf(float f){
  unsigned b = __float_as_uint(f);
  return b ^ ((unsigned)((int)b >> 31) | 0x80000000u);
}
__device__ __forceinline__ float decf(unsigned u){
  unsigned b = (u & 0x80000000u) ? (u ^ 0x80000000u) : ~u;
  return __uint_as_float(b);
}

__device__ __forceinline__ void gload16(const void* g, void* l){
  __builtin_amdgcn_global_load_lds(
      (const __attribute__((address_space(1))) unsigned*)g,
      (__attribute__((address_space(3))) unsigned*)l, 16, 0, 0);
}

// ---------------------------------------------------------------------------
// K1: split W_e (256x256 block of W) into 3 bf16 matrices in stage order
// [ch][split][col][40] (identity k layout, k padded 32->40 shorts for LDS
// bank spread), plus WD[3][256] (distance-col addend), |q|, zero hist/scalars.
// ---------------------------------------------------------------------------
__global__ __launch_bounds__(256) void k1_setup(
    const float* __restrict__ emb, const float* __restrict__ dtab,
    const float* __restrict__ W, const int* __restrict__ srcp,
    short* __restrict__ Wbs, float* __restrict__ WD, float* __restrict__ QN,
    unsigned* __restrict__ SC, unsigned* __restrict__ H0)
{
  int tid = threadIdx.x;
  int gid = blockIdx.x*256 + tid;
  if (gid < 6144) H0[gid] = 0u;          // H0,H1,H2 contiguous (2048 each)
  if (gid == 0){
    SC[0]=0u;                 // MAXE (encoded max logit)
    ((float*)SC)[1]=0.0f;     // SUME
    SC[2]=0u;                 // EQC
    SC[3]=0u;                 // PFX
    SC[4]=(unsigned)TOPK;     // KP (remaining quota)
  }
  if (blockIdx.x < 256){
    int c = blockIdx.x;       // output col (= W row)
    int k = tid;              // k index
    float f = W[(size_t)c*258 + k];
    unsigned u  = __float_as_uint(f);
    unsigned hb = u & 0xffff0000u;
    float r = f - __uint_as_float(hb);
    unsigned mb = __float_as_uint(r) & 0xffff0000u;
    float r2 = r - __uint_as_float(mb);
    unsigned lb = __float_as_uint(r2) & 0xffff0000u;
    int ch = k >> 5, kk = k & 31;
    // stage index st = ch*3 + s, each stage = 256 cols x 40 shorts
    Wbs[((size_t)(ch*3+0)*256 + c)*40 + kk] = (short)(hb>>16);
    Wbs[((size_t)(ch*3+1)*256 + c)*40 + kk] = (short)(mb>>16);
    Wbs[((size_t)(ch*3+2)*256 + c)*40 + kk] = (short)(lb>>16);
  } else {
    int k = tid;
    float w6 = W[(size_t)k*258 + 256], w7 = W[(size_t)k*258 + 257];
    WD[k]     = w6*dtab[0] + w7*dtab[1];
    WD[256+k] = w6*dtab[2] + w7*dtab[3];
    WD[512+k] = w6*dtab[4] + w7*dtab[5];
    int src = srcp[0];
    float qk = emb[(size_t)src*D + k];
    __shared__ float red[256];
    red[tid]=qk*qk; __syncthreads();
    for (int s2=128;s2>0;s2>>=1){ if (tid<s2) red[tid]+=red[tid+s2]; __syncthreads(); }
    if (tid==0) QN[0] = sqrtf(red[0]);
  }
}

// ---------------------------------------------------------------------------
// K2: bf16x3 MFMA GEMM t = x * W_e^T fused with cosine/logit epilogue.
// 512 threads = 8 waves = 4 row-strips(32r) x 2 col-halves(128c): 128x256/blk.
// B-splits LDS-staged per (chunk,split) stage (20KB, double-buffered) via
// global_load_lds; A rows in registers (2 row-frags/wave), split to bf16x3.
// Slot-consistent identity k layout on BOTH operands (HW k-map cancels).
// Per stage: 8 ds_read_b128 feed 16-48 MFMAs (16 MFMA per read at s=0).
// ---------------------------------------------------------------------------
#define SPLIT(x0,x1, AH,AM,AL) do{ float xs[8]={x0.x,x0.y,x0.z,x0.w,x1.x,x1.y,x1.z,x1.w}; \
  _Pragma("unroll") for(int _e=0;_e<8;++_e){ float _f=xs[_e]; unsigned _u=__float_as_uint(_f); \
    unsigned _hb=_u&0xffff0000u; float _r=_f-__uint_as_float(_hb); \
    unsigned _mb=__float_as_uint(_r)&0xffff0000u; float _r2=_r-__uint_as_float(_mb); \
    unsigned _lb=__float_as_uint(_r2)&0xffff0000u; \
    AH[_e]=(short)(_hb>>16); AM[_e]=(short)(_mb>>16); AL[_e]=(short)(_lb>>16);} }while(0)

#define STAGE(bufi, st) do{ if (tid < 256){ \
  const char* _s = (const char*)Wbs + (size_t)(st)*20480; \
  char* _d = (char*)&bst[bufi][0]; \
  _Pragma("unroll") for (int _i=0;_i<5;++_i){ int _o=(_i*256+tid)*16; gload16(_s+_o, _d+_o);} } }while(0)

#define READB(bufi) do{ const short* _bp = &bst[bufi][0] + rdoff; \
  _Pragma("unroll") for (int _bf=0;_bf<8;++_bf) b[_bf] = *(const short8*)(_bp + _bf*640); }while(0)

#define PASS(A0_, A1_) do{ _Pragma("unroll") for (int _bf=0;_bf<8;++_bf){ \
  acc0[_bf] = __builtin_amdgcn_mfma_f32_16x16x32_bf16(A0_, b[_bf], acc0[_bf],0,0,0); \
  acc1[_bf] = __builtin_amdgcn_mfma_f32_16x16x32_bf16(A1_, b[_bf], acc1[_bf],0,0,0); } }while(0)

__global__ __launch_bounds__(512,2) void k2_main(
    const float* __restrict__ emb, const int* __restrict__ dist,
    const int* __restrict__ srcp, const short* __restrict__ Wbs,
    const float* __restrict__ WD, const float* __restrict__ QN,
    float* __restrict__ Sv, unsigned* __restrict__ UK,
    unsigned* __restrict__ SC, unsigned* __restrict__ H0, int N)
{
  int tid = threadIdx.x;
  int wave = tid >> 6;
  int lane = tid & 63;
  int g = lane >> 4;          // k-group within frag
  int c0 = lane & 15;         // A-row-within-frag / B,C col-within-frag
  int rs = wave >> 1;         // row strip 0..3
  int cH = wave & 1;          // col half 0..1
  int blockbase = blockIdx.x*128;

  __shared__ short bst[2][10240];     // 2 x 20KB stage buffers [col][40]
  __shared__ float wdL[3][256];
  __shared__ float qL[256];
  __shared__ float QS[2][128][2];     // [colhalf][rowlocal][{S,Q}]
  __shared__ int   dL[128];
  __shared__ unsigned h[2048];

  // prologue: stage 0 + tables
  STAGE(0, 0);
  for (int i=tid;i<768;i+=512) ((float*)wdL)[i] = WD[i];
  if (tid < 256) qL[tid] = emb[(size_t)srcp[0]*D + tid];
  if (tid < 128){ int rr = blockbase + tid; dL[tid] = (rr<N)? dist[rr] : 3; }
  for (int i=tid;i<2048;i+=512) h[i]=0u;

  int r0 = blockbase + rs*32 + c0;    // A rows of frag 0 / frag 1
  int r1 = r0 + 16;
  const float* xp0 = emb + (size_t)(r0<N? r0 : (N-1))*D + 8*g;
  const float* xp1 = emb + (size_t)(r1<N? r1 : (N-1))*D + 8*g;

  float4 xA0 = *(const float4*)(xp0);
  float4 xA1 = *(const float4*)(xp0+4);
  float4 xB0 = *(const float4*)(xp1);
  float4 xB1 = *(const float4*)(xp1+4);
  float4 nA0,nA1,nB0,nB1;

  f32x4 acc0[8], acc1[8];
  #pragma unroll
  for (int f=0;f<8;++f){ acc0[f]=(f32x4){0.f,0.f,0.f,0.f}; acc1[f]=(f32x4){0.f,0.f,0.f,0.f}; }

  int rdoff = (cH*128 + c0)*40 + g*8;
  short8 b[8];
  short8 ah0,am0,al0,ah1,am1,al1;

  __syncthreads();   // stage 0 complete (implicit vmcnt(0) drain)

  for (int ch=0; ch<8; ++ch){
    int bufA = ch & 1;
    // ---------- stage s=0 (Bh): hh, mh, lh ----------
    SPLIT(xA0,xA1, ah0,am0,al0);
    SPLIT(xB0,xB1, ah1,am1,al1);
    if (ch < 7){
      nA0 = *(const float4*)(xp0 + 32*(ch+1));
      nA1 = *(const float4*)(xp0 + 32*(ch+1) + 4);
      nB0 = *(const float4*)(xp1 + 32*(ch+1));
      nB1 = *(const float4*)(xp1 + 32*(ch+1) + 4);
    }
    STAGE(bufA^1, 3*ch+1);
    READB(bufA);
    PASS(ah0, ah1);   // hh
    PASS(am0, am1);   // mh
    PASS(al0, al1);   // lh
    __syncthreads();
    // ---------- stage s=1 (Bm): hm, mm ----------
    STAGE(bufA, 3*ch+2);
    READB(bufA^1);
    PASS(ah0, ah1);   // hm
    PASS(am0, am1);   // mm
    __syncthreads();
    // ---------- stage s=2 (Bl): hl ----------
    if (ch < 7) STAGE(bufA^1, 3*ch+3);
    READB(bufA);
    PASS(ah0, ah1);   // hl
    if (ch < 7){ xA0=nA0; xA1=nA1; xB0=nB0; xB1=nB1; }
    __syncthreads();
  }

  // ------------------ epilogue ------------------
  // acc{af}[bf][r] = t[blockbase + rs*32 + af*16 + 4g + r][cH*128 + 16bf + c0]
  #pragma unroll
  for (int af=0; af<2; ++af){
    #pragma unroll
    for (int r=0;r<4;++r){
      int rl = rs*32 + af*16 + 4*g + r;
      int dv = dL[rl];
      int di = dv-1; di = di<0?0:(di>2?2:di);
      float S=0.f, Q=0.f;
      #pragma unroll
      for (int bf=0;bf<8;++bf){
        int col = cH*128 + 16*bf + c0;
        float v = (af ? acc1[bf][r] : acc0[bf][r]) + wdL[di][col];
        S = fmaf(v, qL[col], S);
        Q = fmaf(v, v, Q);
      }
      #pragma unroll
      for (int off=1; off<16; off<<=1){ S += __shfl_xor(S,off); Q += __shfl_xor(Q,off); }
      if (c0==0){ QS[cH][rl][0]=S; QS[cH][rl][1]=Q; }
    }
  }
  __syncthreads();

  float sred = -INFINITY;
  if (tid < 128){
    int row = blockbase + tid;
    if (row < N){
      float S = QS[0][tid][0] + QS[1][tid][0];
      float Q = QS[0][tid][1] + QS[1][tid][1];
      int dv = dL[tid];
      float qn = QN[0];
      float den = fmaxf(sqrtf(Q), EPS) * fmaxf(qn, EPS);
      float cosv = S/den;
      float wgt = (dv==1)?1.5f:((dv==2)?2.0f:1.0f);
      float wv = (dv<=2)? cosv*wgt : -INFINITY;
      unsigned u = encf(wv);
      Sv[row]=S; UK[row]=u;
      if (u > 0x007FFFFFu) atomicAdd(&h[u>>21],1u);
      sred = S;
    }
  }
  if (wave < 2){
    float m = sred;
    #pragma unroll
    for (int off=32;off>0;off>>=1) m = fmaxf(m, __shfl_down(m,off));
    if (lane==0) atomicMax(&SC[0], encf(m));
  }
  __syncthreads();
  for (int i=tid;i<2048;i+=512){ unsigned v=h[i]; if (v) atomicAdd(&H0[i], v); }
}

// ---------------------------------------------------------------------------
// Radix-select histogram passes 1,2 (LDS-privatized).  (unchanged)
// ---------------------------------------------------------------------------
__global__ __launch_bounds__(256) void kh_hist(
    const unsigned* __restrict__ UK, const unsigned* __restrict__ SC,
    unsigned* __restrict__ Hp, int pass, int N)
{
  __shared__ unsigned h[2048];
  int bins = (pass==2)?1024:2048;
  int tid = threadIdx.x;
  for (int i=tid;i<bins;i+=256) h[i]=0u;
  __syncthreads();
  unsigned pfx = SC[3];
  int n = blockIdx.x*256 + tid;
  if (n < N){
    unsigned u = UK[n];
    bool incl; unsigned bin;
    if (pass==1){ incl = ((u>>21)==pfx); bin = (u>>10)&2047u; }
    else { incl = ((u>>10)==pfx); bin = u & 1023u; }
    if (incl) atomicAdd(&h[bin], 1u);
  }
  __syncthreads();
  for (int i=tid;i<bins;i+=256){ unsigned v=h[i]; if (v) atomicAdd(&Hp[i], v); }
}

__global__ __launch_bounds__(256) void ks_scan(
    const unsigned* __restrict__ Hp, unsigned* __restrict__ SC, int pass)
{
  __shared__ unsigned h[2048];
  __shared__ unsigned part[256];
  int bins=(pass==2)?1024:2048;
  int per = bins/256;
  int tid=threadIdx.x;
  unsigned ps=0;
  for (int i=0;i<per;++i){ unsigned v=Hp[tid*per+i]; h[tid*per+i]=v; ps+=v; }
  part[tid]=ps;
  __syncthreads();
  if (tid==0){
    unsigned Kp = SC[4];
    unsigned cum=0;
    int sc2=0;
    for (int t=255;t>=0;--t){
      if (cum + part[t] >= Kp){ sc2=t; break; }
      cum += part[t];
    }
    int sel = sc2*per;
    for (int b2=sc2*per+per-1; b2>=sc2*per; --b2){
      if (cum + h[b2] >= Kp){ sel=b2; break; }
      cum += h[b2];
    }
    SC[4] = Kp - cum;                         // remaining quota among == bin
    int bitsp = (pass==2)?10:11;
    SC[3] = (SC[3] << bitsp) | (unsigned)sel; // extend prefix
  }
}

// ---------------------------------------------------------------------------
// K6: write mask (topk-strict | dist==1 | src), collect ==T list, sum-exp.
// (unchanged)
// ---------------------------------------------------------------------------
__global__ __launch_bounds__(256) void k6_final(
    const int* __restrict__ dist, const int* __restrict__ srcp,
    const float* __restrict__ Sv, const unsigned* __restrict__ UK,
    unsigned* __restrict__ SC, unsigned* __restrict__ EQL,
    float* __restrict__ out, int N)
{
  int tid=threadIdx.x;
  int n=blockIdx.x*256+tid;
  unsigned T = SC[3];
  float M = decf(SC[0]);
  int src = srcp[0];
  float e=0.f;
  if (n<N){
    unsigned u = UK[n];
    int dv = dist[n];
    bool base = (u>T) || (dv==1) || (n==src);
    out[1+n] = base ? 1.0f : 0.0f;
    if (u==T){
      unsigned i = atomicAdd(&SC[2], 1u);
      if (i < 4096u) EQL[i] = (unsigned)n;
    }
    e = expf(Sv[n]-M);
  }
  __shared__ float red[256];
  red[tid]=e; __syncthreads();
  for (int st=128;st>0;st>>=1){ if (tid<st) red[tid]+=red[tid+st]; __syncthreads(); }
  if (tid==0) atomicAdd((float*)&SC[1], red[0]);
}

// ---------------------------------------------------------------------------
// K7: loss = L*lse - sum(logits[labels]); resolve ==T ties lowest-index-first.
// (unchanged)
// ---------------------------------------------------------------------------
__global__ __launch_bounds__(256) void k7_loss(
    const int* __restrict__ labels, const float* __restrict__ Sv,
    unsigned* __restrict__ SC, const unsigned* __restrict__ EQL,
    float* __restrict__ out, int L)
{
  __shared__ float red[256];
  __shared__ unsigned lst[4096];
  int tid=threadIdx.x;
  float v=0.f;
  if (tid<L) v = Sv[labels[tid]];
  red[tid]=v; __syncthreads();
  for (int st=128;st>0;st>>=1){ if (tid<st) red[tid]+=red[tid+st]; __syncthreads(); }
  if (tid==0){
    float M = decf(SC[0]);
    float se = ((const float*)SC)[1];
    out[0] = (float)L*(M + logf(se)) - red[0];
  }
  unsigned cnt = SC[2]; if (cnt>4096u) cnt=4096u;
  unsigned quota = SC[4];
  for (unsigned i=tid;i<cnt;i+=256u) lst[i]=EQL[i];
  __syncthreads();
  if (cnt <= quota){
    for (unsigned i=tid;i<cnt;i+=256u) out[1+lst[i]] = 1.0f;
  } else {
    for (unsigned i=tid;i<cnt;i+=256u){
      unsigned me=lst[i]; unsigned rank=0;
      for (unsigned j=0;j<cnt;++j) rank += (lst[j]<me)?1u:0u;
      if (rank<quota) out[1+me]=1.0f;   // stable tie-break: lowest index wins
    }
  }
}

extern "C" void kernel_launch(void* const* d_in, const int* in_sizes, int n_in,
                              void* d_out, int out_size, void* d_ws, size_t ws_size,
                              hipStream_t stream)
{
  const float* emb  = (const float*)d_in[0];
  const float* dtab = (const float*)d_in[1];
  const float* W    = (const float*)d_in[2];
  const int* dist   = (const int*)d_in[3];
  const int* labels = (const int*)d_in[4];
  const int* srcp   = (const int*)d_in[5];
  float* out = (float*)d_out;
  int N = in_sizes[3];
  int L = in_sizes[4];

  float* ws = (float*)d_ws;
  short* Wbs = (short*)ws;              // 24 stages x 256 cols x 40 shorts = 245760 shorts (480KB)
  float* WD  = (float*)(Wbs + 245760);  // 768
  float* QN  = WD + 768;                // 1
  unsigned* SC = (unsigned*)(QN + 1);   // 8 scalars
  unsigned* H0 = SC + 8;                // 2048
  unsigned* H1 = H0 + 2048;             // 2048
  unsigned* H2 = H1 + 2048;             // 2048 (1024 used)
  float* Sv = (float*)(H2 + 2048);      // N
  unsigned* UK = (unsigned*)(Sv + N);   // N
  unsigned* EQL = UK + N;               // 4096

  int grid  = (N + 255)/256;
  int gridm = (N + 127)/128;
  k1_setup<<<257,256,0,stream>>>(emb, dtab, W, srcp, Wbs, WD, QN, SC, H0);
  k2_main<<<gridm,512,0,stream>>>(emb, dist, srcp, Wbs, WD, QN, Sv, UK, SC, H0, N);
  ks_scan<<<1,256,0,stream>>>(H0, SC, 0);
  kh_hist<<<grid,256,0,stream>>>(UK, SC, H1, 1, N);
  ks_scan<<<1,256,0,stream>>>(H1, SC, 1);
  kh_hist<<<grid,256,0,stream>>>(UK, SC, H2, 2, N);
  ks_scan<<<1,256,0,stream>>>(H2, SC, 2);
  k6_final<<<grid,256,0,stream>>>(dist, srcp, Sv, UK, SC, EQL, out, N);
  k7_loss<<<1,256,0,stream>>>(labels, Sv, SC, EQL, out, L);
}